// Round 17
// baseline (1920.281 us; speedup 1.0000x reference)
//
#include <hip/hip_runtime.h>

#define NN 512
#define NR 511
#define NB 64
#define BATCH 256
#define NMAT 257
#define EPSF 1e-7f
#define NN2 ((size_t)NN * NN)

// ---------------- block reduce (512 threads) ----------------
__device__ __forceinline__ float block_reduce_sum_512(float v, float* red) {
#pragma unroll
  for (int off = 32; off > 0; off >>= 1) v += __shfl_down(v, off, 64);
  int tid = threadIdx.x;
  if ((tid & 63) == 0) red[tid >> 6] = v;
  __syncthreads();
  float s = 0.f;
#pragma unroll
  for (int w = 0; w < 8; ++w) s += red[w];
  return s;
}

// ---------------- V = softmax(V_compress, axis=1) ----------------
__global__ void k_softmaxV(const float* __restrict__ Vc, float* __restrict__ V) {
  int i = threadIdx.x;  // 512 threads, 1 block
  float v0 = Vc[i * 4 + 0], v1 = Vc[i * 4 + 1], v2 = Vc[i * 4 + 2], v3 = Vc[i * 4 + 3];
  float mx = fmaxf(fmaxf(v0, v1), fmaxf(v2, v3));
  float e0 = expf(v0 - mx), e1 = expf(v1 - mx), e2 = expf(v2 - mx), e3 = expf(v3 - mx);
  float s = e0 + e1 + e2 + e3;
  V[i * 4 + 0] = e0 / s; V[i * 4 + 1] = e1 / s; V[i * 4 + 2] = e2 / s; V[i * 4 + 3] = e3 / s;
}

// ---------------- Ws[i][j] = sym tril sigmoid ----------------
__global__ void k_Ws(const float* __restrict__ W, float* __restrict__ Ws) {
  int i = blockIdx.x, j = threadIdx.x;
  float v = 0.f;
  if (i != j) {
    int hi = i > j ? i : j, lo = i > j ? j : i;
    float wv = W[hi * NN + lo];
    v = 1.f / (1.f + expf(-wv));
  }
  Ws[i * NN + j] = v;
}

// ---------------- E sinkhorn: per (i,j) independent 4x4 ----------------
// Plane-major output Et[a*4+b][i][j] (16 planes of 512x512).
__global__ void k_E(const float* __restrict__ Ec, const float* __restrict__ V,
                    float* __restrict__ E) {
  int idx = blockIdx.x * blockDim.x + threadIdx.x;  // i*512 + j
  if (idx >= NN * NN) return;
  int i = idx >> 9, j = idx & 511;
  float e[16];
  const float* src = Ec + (size_t)idx * 16;
#pragma unroll
  for (int t = 0; t < 16; ++t) e[t] = expf(src[t]);
  float tot = 0.f;
#pragma unroll
  for (int t = 0; t < 16; ++t) tot += e[t];
  float rt = 1.f / tot;
#pragma unroll
  for (int t = 0; t < 16; ++t) e[t] *= rt;
  float Vi[4], Vj[4];
#pragma unroll
  for (int a = 0; a < 4; ++a) { Vi[a] = V[i * 4 + a]; Vj[a] = V[j * 4 + a]; }
#pragma unroll
  for (int it = 0; it < 2; ++it) {
#pragma unroll
    for (int a = 0; a < 4; ++a) {
      float rs = e[a * 4 + 0] + e[a * 4 + 1] + e[a * 4 + 2] + e[a * 4 + 3];
      float sc = Vi[a] / rs;
#pragma unroll
      for (int b = 0; b < 4; ++b) e[a * 4 + b] *= sc;
    }
#pragma unroll
    for (int b = 0; b < 4; ++b) {
      float cs = e[0 + b] + e[4 + b] + e[8 + b] + e[12 + b];
      float sc = Vj[b] / cs;
#pragma unroll
      for (int a = 0; a < 4; ++a) e[a * 4 + b] *= sc;
    }
    float t2 = 0.f;
#pragma unroll
    for (int t = 0; t < 16; ++t) t2 += e[t];
    float rt2 = 1.f / t2;
#pragma unroll
    for (int t = 0; t < 16; ++t) e[t] *= rt2;
  }
  bool diag = (i == j);
#pragma unroll
  for (int t = 0; t < 16; ++t) {
    float v = diag ? 0.f : e[t];
    E[(size_t)t * NN2 + idx] = fminf(fmaxf(v, 0.f), 1.f);  // coalesced per plane
  }
}

// ---------------- rPr = 1/Pr + sum log(Pr+EPS) ----------------
__global__ __launch_bounds__(512)
void k_Pr(const int* __restrict__ x, const float* __restrict__ V,
          float* __restrict__ rPr, float* __restrict__ logPr) {
  __shared__ float red[8];
  int b = blockIdx.x, i = threadIdx.x;
  int xi = x[b * NN + i];
  float pr = V[i * 4 + xi];
  rPr[b * NN + i] = 1.f / pr;
  float s = block_reduce_sum_512(logf(pr + EPSF), red);
  if (i == 0) logPr[b] = s;
}

// ---------------- build padded 512x512 Laplacian submatrix ----------------
// Wave = one padded row; lane = two wave-contiguous float4 chunks (R16 fix).
__global__ __launch_bounds__(512)
void k_build(const int* __restrict__ x, const float* __restrict__ Ws,
             const float* __restrict__ E, const float* __restrict__ rPr,
             float* __restrict__ mats, int m0) {
  int slot = blockIdx.y;
  int m = m0 + slot;
  float* A = mats + (size_t)slot * NN2;
  int wv = threadIdx.x >> 6, lane = threadIdx.x & 63;
  int r = blockIdx.x * 8 + wv;  // padded row
  int jA = lane * 4;
  int jB = 256 + lane * 4;
  float* dstA = A + (size_t)r * NN + jA;
  float* dstB = A + (size_t)r * NN + jB;
  if (r == NR) {
    float4 z = {0.f, 0.f, 0.f, 0.f};
    float4 z1 = {0.f, 0.f, 0.f, 0.f};
    if (lane == 63) z1.w = 1.f;
    *(float4*)dstA = z;
    *(float4*)dstB = z1;
    return;
  }
  int i = r + 1;   // original row
  float4 wsA = *(const float4*)&Ws[i * NN + jA];
  float4 wsB = *(const float4*)&Ws[i * NN + jB];
  float wpA[4], wpB[4];
  if (m < BATCH) {
    const int* xm = x + (size_t)m * NN;
    int xi = xm[i];
    int4 xa = *(const int4*)&xm[jA];
    int4 xb = *(const int4*)&xm[jB];
    const float* rp = rPr + (size_t)m * NN;
    float rpi = rp[i];
    float4 ra = *(const float4*)&rp[jA];
    float4 rb = *(const float4*)&rp[jB];
    const float* EbA = E + (size_t)(xi * 4) * NN2 + (size_t)i * NN + jA;
    const float* EbB = E + (size_t)(xi * 4) * NN2 + (size_t)i * NN + jB;
    wpA[0] = wsA.x * EbA[(size_t)xa.x * NN2 + 0] * (rpi * ra.x);
    wpA[1] = wsA.y * EbA[(size_t)xa.y * NN2 + 1] * (rpi * ra.y);
    wpA[2] = wsA.z * EbA[(size_t)xa.z * NN2 + 2] * (rpi * ra.z);
    wpA[3] = wsA.w * EbA[(size_t)xa.w * NN2 + 3] * (rpi * ra.w);
    wpB[0] = wsB.x * EbB[(size_t)xb.x * NN2 + 0] * (rpi * rb.x);
    wpB[1] = wsB.y * EbB[(size_t)xb.y * NN2 + 1] * (rpi * rb.y);
    wpB[2] = wsB.z * EbB[(size_t)xb.z * NN2 + 2] * (rpi * rb.z);
    wpB[3] = wsB.w * EbB[(size_t)xb.w * NN2 + 3] * (rpi * rb.w);
  } else {  // L_0 matrix
    wpA[0] = wsA.x; wpA[1] = wsA.y; wpA[2] = wsA.z; wpA[3] = wsA.w;
    wpB[0] = wsB.x; wpB[1] = wsB.y; wpB[2] = wsB.z; wpB[3] = wsB.w;
  }
  float rs = ((wpA[0] + wpA[1]) + (wpA[2] + wpA[3])) +
             ((wpB[0] + wpB[1]) + (wpB[2] + wpB[3]));
#pragma unroll
  for (int o = 32; o > 0; o >>= 1) rs += __shfl_xor(rs, o, 64);
  float nxtA = __shfl(wpA[0], lane + 1, 64);
  float bndB = __shfl(wpB[0], 0, 64);
  float nxtB = __shfl(wpB[0], lane + 1, 64);
  float shA[4] = {wpA[1], wpA[2], wpA[3], (lane == 63) ? bndB : nxtA};
  float shB[4] = {wpB[1], wpB[2], wpB[3], nxtB};
  float4 oA, oB;
  {
    float o0[4], o1[4];
#pragma unroll
    for (int t = 0; t < 4; ++t) {
      int c = jA + t;
      float v = -shA[t] + EPSF;
      if (c == r) v += rs;
      o0[t] = v;
    }
#pragma unroll
    for (int t = 0; t < 4; ++t) {
      int c = jB + t;
      float v = -shB[t] + EPSF;
      if (c == r) v += rs;
      if (c == NR) v = 0.f;  // pad column
      o1[t] = v;
    }
    oA = {o0[0], o0[1], o0[2], o0[3]};
    oB = {o1[0], o1[1], o1[2], o1[3]};
  }
  *(float4*)dstA = oA;
  *(float4*)dstB = oB;
}

// ---------------- panel step: rows in registers, float4 Prow reads ----------
template <int S>
struct PStepF {
  static __device__ __forceinline__ void run(float (&rr)[64], float (*Prow)[64],
                                             bool own, int tid, float& lgsum) {
    float rinv = 1.f / Prow[S & 1][S];
    if (own && tid > S) {
      float l = rr[S] * rinv;
      rr[S] = l;
      constexpr int C0 = S + 1;
      constexpr int A4 = (C0 + 3) & ~3;
#pragma unroll
      for (int c = C0; c < (A4 < 64 ? A4 : 64); ++c)
        rr[c] = fmaf(-l, Prow[S & 1][c], rr[c]);
#pragma unroll
      for (int g = A4 / 4; g < 16; ++g) {
        float4 u = *(const float4*)&Prow[S & 1][g * 4];
        rr[g * 4 + 0] = fmaf(-l, u.x, rr[g * 4 + 0]);
        rr[g * 4 + 1] = fmaf(-l, u.y, rr[g * 4 + 1]);
        rr[g * 4 + 2] = fmaf(-l, u.z, rr[g * 4 + 2]);
        rr[g * 4 + 3] = fmaf(-l, u.w, rr[g * 4 + 3]);
      }
    }
    if (S + 1 < 64) {
      if (tid == S + 1) {
        lgsum += logf(rr[S + 1]);
#pragma unroll
        for (int c4 = (S + 1) >> 2; c4 < 16; ++c4) {
          float4 v = {rr[c4 * 4 + 0], rr[c4 * 4 + 1], rr[c4 * 4 + 2], rr[c4 * 4 + 3]};
          *(float4*)&Prow[(S + 1) & 1][c4 * 4] = v;
        }
      }
    }
    __syncthreads();
    PStepF<S + 1>::run(rr, Prow, own, tid, lgsum);
  }
};
template <>
struct PStepF<64> {
  static __device__ __forceinline__ void run(float (&)[64], float (*)[64],
                                             bool, int, float&) {}
};

// ---------------- U11^{-1} via compile-time back-substitution ---------------
// Thread j computes column j of X = U11^{-1} in REGISTERS (x[64], all indices
// compile-time -> no scratch). U rows read b128 from L11 (packed LU, stride
// 68). x[R] for R > j naturally evaluates to 0.
template <int R>
struct BackU {
  static __device__ __forceinline__ void run(float (&x)[64], const float* L,
                                             int j) {
    float acc = (j == R) ? 1.f : 0.f;
    constexpr int C0 = R + 1;
    constexpr int A4 = (C0 + 3) & ~3;
#pragma unroll
    for (int c = C0; c < (A4 < 64 ? A4 : 64); ++c)
      acc = fmaf(-L[R * 68 + c], x[c], acc);
#pragma unroll
    for (int g = A4 / 4; g < 16; ++g) {
      float4 u = *(const float4*)&L[R * 68 + g * 4];
      acc = fmaf(-u.x, x[g * 4 + 0], acc);
      acc = fmaf(-u.y, x[g * 4 + 1], acc);
      acc = fmaf(-u.z, x[g * 4 + 2], acc);
      acc = fmaf(-u.w, x[g * 4 + 3], acc);
    }
    x[R] = acc / L[R * 68 + R];
    BackU<R - 1>::run(x, L, j);
  }
};
template <>
struct BackU<-1> {
  static __device__ __forceinline__ void run(float (&)[64], const float*, int) {}
};

// ---------------- U12 step: column in registers, L11 LDS stride 68 ----------
template <int Q>
struct UStep {
  static __device__ __forceinline__ void run(float (&a)[64], const float* L) {
    constexpr int j0 = Q * 4;
    a[j0 + 1] = fmaf(-L[(j0 + 1) * 68 + j0], a[j0], a[j0 + 1]);
    a[j0 + 2] = fmaf(-L[(j0 + 2) * 68 + j0], a[j0], a[j0 + 2]);
    a[j0 + 2] = fmaf(-L[(j0 + 2) * 68 + j0 + 1], a[j0 + 1], a[j0 + 2]);
    a[j0 + 3] = fmaf(-L[(j0 + 3) * 68 + j0], a[j0], a[j0 + 3]);
    a[j0 + 3] = fmaf(-L[(j0 + 3) * 68 + j0 + 1], a[j0 + 1], a[j0 + 3]);
    a[j0 + 3] = fmaf(-L[(j0 + 3) * 68 + j0 + 2], a[j0 + 2], a[j0 + 3]);
#pragma unroll
    for (int t = j0 + 4; t < 64; ++t) {
      float4 Lv = *(const float4*)&L[t * 68 + j0];  // broadcast, 16B-aligned
      float v = a[t];
      v = fmaf(-Lv.x, a[j0 + 0], v);
      v = fmaf(-Lv.y, a[j0 + 1], v);
      v = fmaf(-Lv.z, a[j0 + 2], v);
      v = fmaf(-Lv.w, a[j0 + 3], v);
      a[t] = v;
    }
    UStep<Q + 1>::run(a, L);
  }
};
template <>
struct UStep<16> {
  static __device__ __forceinline__ void run(float (&)[64], const float*) {}
};

// ---------------- panel-lite: pivot block (wave 0) + U11inv + U12 -----------
// Bulk-row elimination moved OUT to k_l21 (GEMM vs U11inv) — k_pu's 8-wave
// 520-b128-per-thread bulk phase was the dominant LDS-issue cost (~40us).
// Wave 0: PStepF on pivot rows only (16 LDS instr/step), publish L11, then
// BackU computes U11inv columns in registers (overlapped with U12 on waves
// 1-7). U12 unchanged.
__global__ __launch_bounds__(512)
void k_pu(float* __restrict__ mats, float* __restrict__ ld,
          float* __restrict__ Uinv, int m0, int p) {
  __shared__ __align__(16) float L11[64 * 68];   // 17.4 KB
  __shared__ __align__(16) float Prow[2][64];
  __shared__ float red[8];
  int slot = blockIdx.x;
  float* A = mats + (size_t)slot * NN2;
  int tid = threadIdx.x;
  int k0 = p * NB;
  int w = NN - k0 - NB;
  float lgsum = 0.f;
  float rr[64];

  // ---- phase A: pivot-block factorization (wave 0 rows only) ----
  if (tid < 64) {
    const float* myrow = A + (size_t)(k0 + tid) * NN + k0;
#pragma unroll
    for (int c4 = 0; c4 < 16; ++c4) {
      float4 v = *(const float4*)(myrow + c4 * 4);
      rr[c4 * 4 + 0] = v.x; rr[c4 * 4 + 1] = v.y;
      rr[c4 * 4 + 2] = v.z; rr[c4 * 4 + 3] = v.w;
    }
  } else {
#pragma unroll
    for (int c = 0; c < 64; ++c) rr[c] = 0.f;
  }
  if (tid == 0) {
    lgsum += logf(rr[0]);
#pragma unroll
    for (int c4 = 0; c4 < 16; ++c4) {
      float4 v = {rr[c4 * 4 + 0], rr[c4 * 4 + 1], rr[c4 * 4 + 2], rr[c4 * 4 + 3]};
      *(float4*)&Prow[0][c4 * 4] = v;
    }
  }
  __syncthreads();
  PStepF<0>::run(rr, Prow, tid < 64, tid, lgsum);
  if (tid < 64) {  // publish packed LU rows (L mult + U) for U12 + BackU
#pragma unroll
    for (int c4 = 0; c4 < 16; ++c4) {
      float4 v = {rr[c4 * 4 + 0], rr[c4 * 4 + 1], rr[c4 * 4 + 2], rr[c4 * 4 + 3]};
      *(float4*)&L11[tid * 68 + c4 * 4] = v;
    }
  }
  __syncthreads();

  // ---- phase B (waves 1-7 + wave 0 after BackU): U12 = L11^{-1} A12 ----
  // ---- wave 0 first: U11inv column tid -> global scratch ----
  if (tid < 64 && w > 0) {
    BackU<63>::run(rr, L11, tid);  // rr reused as x[] (L11 already published)
    float* Ug = Uinv + (size_t)slot * 4096;
#pragma unroll
    for (int r = 0; r < 64; ++r) Ug[r * 64 + tid] = rr[r];  // coalesced per r
  }
  if (w > 0 && tid < w) {
    int col = k0 + NB + tid;
#pragma unroll
    for (int t = 0; t < 64; ++t) rr[t] = A[(size_t)(k0 + t) * NN + col];
    UStep<0>::run(rr, L11);
#pragma unroll
    for (int t = 0; t < 64; ++t) A[(size_t)(k0 + t) * NN + col] = rr[t];
  }

  // ---- logdet partial ----
  float s = block_reduce_sum_512(lgsum, red);
  if (tid == 0) {
    int gi = m0 + slot;
    if (p == 0) ld[gi] = s;
    else        ld[gi] += s;
  }
}

// ---------------- L21 = A21 * U11inv (TRSM as GEMM, pure overwrite) ---------
// grid (ceil(w/128), cnt), 256 threads. A21 tile transposed in LDS [kk][r]
// stride 132; U11inv (16KB) staged in LDS. Thread = 4 rows x 8 cols.
__global__ __launch_bounds__(256)
void k_l21(float* __restrict__ mats, const float* __restrict__ Uinv, int p) {
  __shared__ __align__(16) float Atk[64 * 132];  // 33.8 KB
  __shared__ __align__(16) float UiL[64 * 64];   // 16 KB
  int k0 = p * NB;
  int w = NN - k0 - NB;
  float* A = mats + (size_t)blockIdx.y * NN2;
  const float* Ug = Uinv + (size_t)blockIdx.y * 4096;
  int rb = blockIdx.x * 128;
  int tid = threadIdx.x;
#pragma unroll
  for (int it = 0; it < 32; ++it) {  // stage A21 tile (transposed)
    int idx = tid + it * 256;
    int r = idx >> 6, kk = idx & 63;
    int gr = rb + r;
    float v = 0.f;
    if (gr < w) v = A[(size_t)(k0 + NB + gr) * NN + k0 + kk];
    Atk[kk * 132 + r] = v;
  }
#pragma unroll
  for (int it = 0; it < 16; ++it) {  // stage U11inv (row-major)
    int idx = tid + it * 256;
    UiL[idx] = Ug[idx];
  }
  __syncthreads();
  int tx = tid & 7, ty = tid >> 3;   // 8 col-groups x 32 row-groups
  int c0 = tx * 8, r0 = ty * 4;
  float acc[4][8];
#pragma unroll
  for (int q = 0; q < 4; ++q)
#pragma unroll
    for (int u = 0; u < 8; ++u) acc[q][u] = 0.f;
#pragma unroll 4
  for (int kk = 0; kk < 64; ++kk) {
    float4 a0 = *(const float4*)&Atk[kk * 132 + r0];
    float4 b0 = *(const float4*)&UiL[kk * 64 + c0];
    float4 b1 = *(const float4*)&UiL[kk * 64 + c0 + 4];
    float la[4] = {a0.x, a0.y, a0.z, a0.w};
    float lb[8] = {b0.x, b0.y, b0.z, b0.w, b1.x, b1.y, b1.z, b1.w};
#pragma unroll
    for (int q = 0; q < 4; ++q)
#pragma unroll
      for (int u = 0; u < 8; ++u) acc[q][u] = fmaf(la[q], lb[u], acc[q][u]);
  }
#pragma unroll
  for (int q = 0; q < 4; ++q) {
    int gr = rb + r0 + q;
    if (gr < w) {
      float* dst = &A[(size_t)(k0 + NB + gr) * NN + k0 + c0];
      float4 v0 = {acc[q][0], acc[q][1], acc[q][2], acc[q][3]};
      float4 v1 = {acc[q][4], acc[q][5], acc[q][6], acc[q][7]};
      *(float4*)dst = v0;
      *(float4*)(dst + 4) = v1;
    }
  }
}

// ---------------- trailing update A22 -= L21 * U12 ----------------
// grid (nt, nt, count), 256 threads, 128x128 tile, k = 64.
// At transposed [kk][r] stride 136; B-operand pipelined DEPTH 3 (named f4s).
__global__ __launch_bounds__(256)
void k_gemm(float* __restrict__ mats, int p) {
  __shared__ __align__(16) float At[64 * 136];  // 34.8 KB
  int k0 = p * NB;
  int w = NN - k0 - NB;
  float* A = mats + (size_t)blockIdx.z * NN2;
  int rb = blockIdx.x * 128, cb = blockIdx.y * 128;
  int tid = threadIdx.x;
#pragma unroll
  for (int it = 0; it < 32; ++it) {
    int idx = tid + it * 256;
    int r = idx >> 6, kk = idx & 63;
    int gr = rb + r;
    float v = 0.f;
    if (gr < w) v = A[(size_t)(k0 + NB + gr) * NN + k0 + kk];
    At[kk * 136 + r] = v;
  }
  __syncthreads();
  int ty = tid >> 4, tx = tid & 15;
  int r0 = ty * 8, c0 = tx * 8;
  int gc0 = k0 + NB + cb + c0;
  bool cok = (cb + c0) < w;
  float acc[8][8];
#pragma unroll
  for (int q = 0; q < 8; ++q)
#pragma unroll
    for (int u = 0; u < 8; ++u) acc[q][u] = 0.f;
  float4 bc0 = {0.f, 0.f, 0.f, 0.f}, bc1 = {0.f, 0.f, 0.f, 0.f};
  float4 bn0 = {0.f, 0.f, 0.f, 0.f}, bn1 = {0.f, 0.f, 0.f, 0.f};
  float4 bf0 = {0.f, 0.f, 0.f, 0.f}, bf1 = {0.f, 0.f, 0.f, 0.f};
  if (cok) {
    const float* Br0 = &A[(size_t)k0 * NN + gc0];
    bc0 = *(const float4*)Br0;
    bc1 = *(const float4*)(Br0 + 4);
    const float* Br1 = &A[(size_t)(k0 + 1) * NN + gc0];
    bn0 = *(const float4*)Br1;
    bn1 = *(const float4*)(Br1 + 4);
    const float* Br2 = &A[(size_t)(k0 + 2) * NN + gc0];
    bf0 = *(const float4*)Br2;
    bf1 = *(const float4*)(Br2 + 4);
  }
#pragma unroll 2
  for (int kk = 0; kk < 64; ++kk) {
    float4 bx0 = {0.f, 0.f, 0.f, 0.f}, bx1 = {0.f, 0.f, 0.f, 0.f};
    if (cok && kk < 61) {
      const float* Br = &A[(size_t)(k0 + kk + 3) * NN + gc0];
      bx0 = *(const float4*)Br;
      bx1 = *(const float4*)(Br + 4);
    }
    float4 a0 = *(const float4*)&At[kk * 136 + r0];
    float4 a1 = *(const float4*)&At[kk * 136 + r0 + 4];
    float la[8] = {a0.x, a0.y, a0.z, a0.w, a1.x, a1.y, a1.z, a1.w};
    float lb[8] = {bc0.x, bc0.y, bc0.z, bc0.w, bc1.x, bc1.y, bc1.z, bc1.w};
#pragma unroll
    for (int q = 0; q < 8; ++q)
#pragma unroll
      for (int u = 0; u < 8; ++u) acc[q][u] = fmaf(la[q], lb[u], acc[q][u]);
    bc0 = bn0; bc1 = bn1;
    bn0 = bf0; bn1 = bf1;
    bf0 = bx0; bf1 = bx1;
  }
  if (!cok) return;
#pragma unroll
  for (int q = 0; q < 8; ++q) {
    int gr = rb + r0 + q;
    if (gr < w) {
      float* dst = &A[(size_t)(k0 + NB + gr) * NN + gc0];
      float4 v0 = *(const float4*)dst;
      float4 v1 = *(const float4*)(dst + 4);
      v0.x -= acc[q][0]; v0.y -= acc[q][1]; v0.z -= acc[q][2]; v0.w -= acc[q][3];
      v1.x -= acc[q][4]; v1.y -= acc[q][5]; v1.z -= acc[q][6]; v1.w -= acc[q][7];
      *(float4*)dst = v0;
      *(float4*)(dst + 4) = v1;
    }
  }
}

// ---------------- final combine ----------------
__global__ void k_y(const float* __restrict__ logPr, const float* __restrict__ ld,
                    float* __restrict__ y) {
  int b = threadIdx.x;
  if (b < BATCH) y[b] = logPr[b] + ld[b] - ld[BATCH];
}

extern "C" void kernel_launch(void* const* d_in, const int* in_sizes, int n_in,
                              void* d_out, int out_size, void* d_ws, size_t ws_size,
                              hipStream_t stream) {
  const int* x = (const int*)d_in[0];
  const float* W = (const float*)d_in[1];
  const float* Vc = (const float*)d_in[2];
  const float* Ec = (const float*)d_in[3];
  float* out = (float*)d_out;

  char* ws = (char*)d_ws;
  size_t off = 0;
  auto alloc = [&](size_t bytes) -> void* {
    void* pp = ws + off;
    off = (off + bytes + 255) & ~(size_t)255;
    return pp;
  };
  float* V     = (float*)alloc((size_t)NN * 4 * 4);
  float* Wsbuf = (float*)alloc(NN2 * 4);
  float* rPr   = (float*)alloc((size_t)BATCH * NN * 4);
  float* logPr = (float*)alloc((size_t)BATCH * 4);
  float* ld    = (float*)alloc((size_t)NMAT * 4);
  float* E     = (float*)alloc(NN2 * 16 * 4);
  float* Uinv  = (float*)alloc((size_t)NMAT * 4096 * 4);  // 4.2 MB
  size_t per_mat = NN2 * 4;
  size_t remain = ws_size > off ? ws_size - off : 0;
  int cap = (int)(remain / per_mat);
  if (cap > NMAT) cap = NMAT;
  if (cap < 1) cap = 1;
  float* mats = (float*)(ws + off);

  k_softmaxV<<<1, 512, 0, stream>>>(Vc, V);
  k_Ws<<<NN, NN, 0, stream>>>(W, Wsbuf);
  k_E<<<(NN * NN) / 256, 256, 0, stream>>>(Ec, V, E);
  k_Pr<<<BATCH, NN, 0, stream>>>(x, V, rPr, logPr);

  for (int m0 = 0; m0 < NMAT; m0 += cap) {
    int cnt = NMAT - m0 < cap ? NMAT - m0 : cap;
    dim3 gb(64, cnt);
    k_build<<<gb, 512, 0, stream>>>(x, Wsbuf, E, rPr, mats, m0);
    for (int p = 0; p < 8; ++p) {
      k_pu<<<cnt, 512, 0, stream>>>(mats, ld, Uinv, m0, p);
      int w = NN - p * NB - NB;
      if (w > 0) {
        dim3 gl((w + 127) / 128, cnt);
        k_l21<<<gl, 256, 0, stream>>>(mats, Uinv, p);
        int nt = (w + 127) / 128;
        dim3 gg(nt, nt, cnt);
        k_gemm<<<gg, 256, 0, stream>>>(mats, p);
      }
    }
  }
  k_y<<<1, 256, 0, stream>>>(logPr, ld, out);
}

// Round 18
// 1547.987 us; speedup vs baseline: 1.2405x; 1.2405x over previous
//
#include <hip/hip_runtime.h>

#define NN 512
#define NR 511
#define NB 64
#define BATCH 256
#define NMAT 257
#define EPSF 1e-7f
#define NN2 ((size_t)NN * NN)

// ---------------- block reduce (512 threads) ----------------
__device__ __forceinline__ float block_reduce_sum_512(float v, float* red) {
#pragma unroll
  for (int off = 32; off > 0; off >>= 1) v += __shfl_down(v, off, 64);
  int tid = threadIdx.x;
  if ((tid & 63) == 0) red[tid >> 6] = v;
  __syncthreads();
  float s = 0.f;
#pragma unroll
  for (int w = 0; w < 8; ++w) s += red[w];
  return s;
}

// ---------------- V = softmax(V_compress, axis=1) ----------------
__global__ void k_softmaxV(const float* __restrict__ Vc, float* __restrict__ V) {
  int i = threadIdx.x;  // 512 threads, 1 block
  float v0 = Vc[i * 4 + 0], v1 = Vc[i * 4 + 1], v2 = Vc[i * 4 + 2], v3 = Vc[i * 4 + 3];
  float mx = fmaxf(fmaxf(v0, v1), fmaxf(v2, v3));
  float e0 = expf(v0 - mx), e1 = expf(v1 - mx), e2 = expf(v2 - mx), e3 = expf(v3 - mx);
  float s = e0 + e1 + e2 + e3;
  V[i * 4 + 0] = e0 / s; V[i * 4 + 1] = e1 / s; V[i * 4 + 2] = e2 / s; V[i * 4 + 3] = e3 / s;
}

// ---------------- Ws[i][j] = sym tril sigmoid ----------------
__global__ void k_Ws(const float* __restrict__ W, float* __restrict__ Ws) {
  int i = blockIdx.x, j = threadIdx.x;
  float v = 0.f;
  if (i != j) {
    int hi = i > j ? i : j, lo = i > j ? j : i;
    float wv = W[hi * NN + lo];
    v = 1.f / (1.f + expf(-wv));
  }
  Ws[i * NN + j] = v;
}

// ---------------- E sinkhorn: per (i,j) independent 4x4 ----------------
// Plane-major output Et[a*4+b][i][j] (16 planes of 512x512).
__global__ void k_E(const float* __restrict__ Ec, const float* __restrict__ V,
                    float* __restrict__ E) {
  int idx = blockIdx.x * blockDim.x + threadIdx.x;  // i*512 + j
  if (idx >= NN * NN) return;
  int i = idx >> 9, j = idx & 511;
  float e[16];
  const float* src = Ec + (size_t)idx * 16;
#pragma unroll
  for (int t = 0; t < 16; ++t) e[t] = expf(src[t]);
  float tot = 0.f;
#pragma unroll
  for (int t = 0; t < 16; ++t) tot += e[t];
  float rt = 1.f / tot;
#pragma unroll
  for (int t = 0; t < 16; ++t) e[t] *= rt;
  float Vi[4], Vj[4];
#pragma unroll
  for (int a = 0; a < 4; ++a) { Vi[a] = V[i * 4 + a]; Vj[a] = V[j * 4 + a]; }
#pragma unroll
  for (int it = 0; it < 2; ++it) {
#pragma unroll
    for (int a = 0; a < 4; ++a) {
      float rs = e[a * 4 + 0] + e[a * 4 + 1] + e[a * 4 + 2] + e[a * 4 + 3];
      float sc = Vi[a] / rs;
#pragma unroll
      for (int b = 0; b < 4; ++b) e[a * 4 + b] *= sc;
    }
#pragma unroll
    for (int b = 0; b < 4; ++b) {
      float cs = e[0 + b] + e[4 + b] + e[8 + b] + e[12 + b];
      float sc = Vj[b] / cs;
#pragma unroll
      for (int a = 0; a < 4; ++a) e[a * 4 + b] *= sc;
    }
    float t2 = 0.f;
#pragma unroll
    for (int t = 0; t < 16; ++t) t2 += e[t];
    float rt2 = 1.f / t2;
#pragma unroll
    for (int t = 0; t < 16; ++t) e[t] *= rt2;
  }
  bool diag = (i == j);
#pragma unroll
  for (int t = 0; t < 16; ++t) {
    float v = diag ? 0.f : e[t];
    E[(size_t)t * NN2 + idx] = fminf(fmaxf(v, 0.f), 1.f);  // coalesced per plane
  }
}

// ---------------- rPr = 1/Pr + sum log(Pr+EPS) ----------------
__global__ __launch_bounds__(512)
void k_Pr(const int* __restrict__ x, const float* __restrict__ V,
          float* __restrict__ rPr, float* __restrict__ logPr) {
  __shared__ float red[8];
  int b = blockIdx.x, i = threadIdx.x;
  int xi = x[b * NN + i];
  float pr = V[i * 4 + xi];
  rPr[b * NN + i] = 1.f / pr;
  float s = block_reduce_sum_512(logf(pr + EPSF), red);
  if (i == 0) logPr[b] = s;
}

// ---------------- build padded 512x512 Laplacian submatrix ----------------
// Wave = one padded row; lane = two wave-contiguous float4 chunks (R16 fix).
__global__ __launch_bounds__(512)
void k_build(const int* __restrict__ x, const float* __restrict__ Ws,
             const float* __restrict__ E, const float* __restrict__ rPr,
             float* __restrict__ mats, int m0) {
  int slot = blockIdx.y;
  int m = m0 + slot;
  float* A = mats + (size_t)slot * NN2;
  int wv = threadIdx.x >> 6, lane = threadIdx.x & 63;
  int r = blockIdx.x * 8 + wv;  // padded row
  int jA = lane * 4;
  int jB = 256 + lane * 4;
  float* dstA = A + (size_t)r * NN + jA;
  float* dstB = A + (size_t)r * NN + jB;
  if (r == NR) {
    float4 z = {0.f, 0.f, 0.f, 0.f};
    float4 z1 = {0.f, 0.f, 0.f, 0.f};
    if (lane == 63) z1.w = 1.f;
    *(float4*)dstA = z;
    *(float4*)dstB = z1;
    return;
  }
  int i = r + 1;   // original row
  float4 wsA = *(const float4*)&Ws[i * NN + jA];
  float4 wsB = *(const float4*)&Ws[i * NN + jB];
  float wpA[4], wpB[4];
  if (m < BATCH) {
    const int* xm = x + (size_t)m * NN;
    int xi = xm[i];
    int4 xa = *(const int4*)&xm[jA];
    int4 xb = *(const int4*)&xm[jB];
    const float* rp = rPr + (size_t)m * NN;
    float rpi = rp[i];
    float4 ra = *(const float4*)&rp[jA];
    float4 rb = *(const float4*)&rp[jB];
    const float* EbA = E + (size_t)(xi * 4) * NN2 + (size_t)i * NN + jA;
    const float* EbB = E + (size_t)(xi * 4) * NN2 + (size_t)i * NN + jB;
    wpA[0] = wsA.x * EbA[(size_t)xa.x * NN2 + 0] * (rpi * ra.x);
    wpA[1] = wsA.y * EbA[(size_t)xa.y * NN2 + 1] * (rpi * ra.y);
    wpA[2] = wsA.z * EbA[(size_t)xa.z * NN2 + 2] * (rpi * ra.z);
    wpA[3] = wsA.w * EbA[(size_t)xa.w * NN2 + 3] * (rpi * ra.w);
    wpB[0] = wsB.x * EbB[(size_t)xb.x * NN2 + 0] * (rpi * rb.x);
    wpB[1] = wsB.y * EbB[(size_t)xb.y * NN2 + 1] * (rpi * rb.y);
    wpB[2] = wsB.z * EbB[(size_t)xb.z * NN2 + 2] * (rpi * rb.z);
    wpB[3] = wsB.w * EbB[(size_t)xb.w * NN2 + 3] * (rpi * rb.w);
  } else {  // L_0 matrix
    wpA[0] = wsA.x; wpA[1] = wsA.y; wpA[2] = wsA.z; wpA[3] = wsA.w;
    wpB[0] = wsB.x; wpB[1] = wsB.y; wpB[2] = wsB.z; wpB[3] = wsB.w;
  }
  float rs = ((wpA[0] + wpA[1]) + (wpA[2] + wpA[3])) +
             ((wpB[0] + wpB[1]) + (wpB[2] + wpB[3]));
#pragma unroll
  for (int o = 32; o > 0; o >>= 1) rs += __shfl_xor(rs, o, 64);
  float nxtA = __shfl(wpA[0], lane + 1, 64);
  float bndB = __shfl(wpB[0], 0, 64);
  float nxtB = __shfl(wpB[0], lane + 1, 64);
  float shA[4] = {wpA[1], wpA[2], wpA[3], (lane == 63) ? bndB : nxtA};
  float shB[4] = {wpB[1], wpB[2], wpB[3], nxtB};
  float4 oA, oB;
  {
    float o0[4], o1[4];
#pragma unroll
    for (int t = 0; t < 4; ++t) {
      int c = jA + t;
      float v = -shA[t] + EPSF;
      if (c == r) v += rs;
      o0[t] = v;
    }
#pragma unroll
    for (int t = 0; t < 4; ++t) {
      int c = jB + t;
      float v = -shB[t] + EPSF;
      if (c == r) v += rs;
      if (c == NR) v = 0.f;  // pad column
      o1[t] = v;
    }
    oA = {o0[0], o0[1], o0[2], o0[3]};
    oB = {o1[0], o1[1], o1[2], o1[3]};
  }
  *(float4*)dstA = oA;
  *(float4*)dstB = oB;
}

// ---------------- panel step: rows in registers, float4 Prow reads ----------
// R12/R16-proven (best). 64 barriered rank-1 steps, all waves in parallel.
// (Failed alternatives: R10 wave-sync -160us, R13 rank-4 cascade -110us,
// R17 TRSM-split -368us — panel is LDS-read-volume-bound, structure optimal.)
template <int S>
struct PStepF {
  static __device__ __forceinline__ void run(float (&rr)[64], float (*Prow)[64],
                                             bool own, int tid, float& lgsum) {
    float rinv = 1.f / Prow[S & 1][S];
    if (own && tid > S) {
      float l = rr[S] * rinv;
      rr[S] = l;
      constexpr int C0 = S + 1;
      constexpr int A4 = (C0 + 3) & ~3;
#pragma unroll
      for (int c = C0; c < (A4 < 64 ? A4 : 64); ++c)
        rr[c] = fmaf(-l, Prow[S & 1][c], rr[c]);
#pragma unroll
      for (int g = A4 / 4; g < 16; ++g) {
        float4 u = *(const float4*)&Prow[S & 1][g * 4];
        rr[g * 4 + 0] = fmaf(-l, u.x, rr[g * 4 + 0]);
        rr[g * 4 + 1] = fmaf(-l, u.y, rr[g * 4 + 1]);
        rr[g * 4 + 2] = fmaf(-l, u.z, rr[g * 4 + 2]);
        rr[g * 4 + 3] = fmaf(-l, u.w, rr[g * 4 + 3]);
      }
    }
    if (S + 1 < 64) {
      if (tid == S + 1) {
        lgsum += logf(rr[S + 1]);
#pragma unroll
        for (int c4 = (S + 1) >> 2; c4 < 16; ++c4) {
          float4 v = {rr[c4 * 4 + 0], rr[c4 * 4 + 1], rr[c4 * 4 + 2], rr[c4 * 4 + 3]};
          *(float4*)&Prow[(S + 1) & 1][c4 * 4] = v;
        }
      }
    }
    __syncthreads();
    PStepF<S + 1>::run(rr, Prow, own, tid, lgsum);
  }
};
template <>
struct PStepF<64> {
  static __device__ __forceinline__ void run(float (&)[64], float (*)[64],
                                             bool, int, float&) {}
};

// ---------------- U12 step: column in registers, L11 LDS stride 68 ----------
template <int Q>
struct UStep {
  static __device__ __forceinline__ void run(float (&a)[64], const float* L) {
    constexpr int j0 = Q * 4;
    a[j0 + 1] = fmaf(-L[(j0 + 1) * 68 + j0], a[j0], a[j0 + 1]);
    a[j0 + 2] = fmaf(-L[(j0 + 2) * 68 + j0], a[j0], a[j0 + 2]);
    a[j0 + 2] = fmaf(-L[(j0 + 2) * 68 + j0 + 1], a[j0 + 1], a[j0 + 2]);
    a[j0 + 3] = fmaf(-L[(j0 + 3) * 68 + j0], a[j0], a[j0 + 3]);
    a[j0 + 3] = fmaf(-L[(j0 + 3) * 68 + j0 + 1], a[j0 + 1], a[j0 + 3]);
    a[j0 + 3] = fmaf(-L[(j0 + 3) * 68 + j0 + 2], a[j0 + 2], a[j0 + 3]);
#pragma unroll
    for (int t = j0 + 4; t < 64; ++t) {
      float4 Lv = *(const float4*)&L[t * 68 + j0];  // broadcast, 16B-aligned
      float v = a[t];
      v = fmaf(-Lv.x, a[j0 + 0], v);
      v = fmaf(-Lv.y, a[j0 + 1], v);
      v = fmaf(-Lv.z, a[j0 + 2], v);
      v = fmaf(-Lv.w, a[j0 + 3], v);
      a[t] = v;
    }
    UStep<Q + 1>::run(a, L);
  }
};
template <>
struct UStep<16> {
  static __device__ __forceinline__ void run(float (&)[64], const float*) {}
};

// ---------------- fused panel + U12 (R16-proven structure) -------------------
// PLAIN __launch_bounds__(512): (512,4) capped VGPR at 64 and spilled rr[64]
// (R5/R8 evidence). Compiler picks ~100 VGPR -> no spill, 2 blocks/CU.
__global__ __launch_bounds__(512)
void k_pu(float* __restrict__ mats, float* __restrict__ ld, int m0, int p) {
  __shared__ __align__(16) float L11[64 * 68];   // 17.4 KB
  __shared__ __align__(16) float Prow[2][64];
  __shared__ float red[8];
  int slot = blockIdx.x;
  float* A = mats + (size_t)slot * NN2;
  int tid = threadIdx.x;
  int k0 = p * NB;
  int m = NN - k0;
  int w = m - NB;
  bool own = tid < m;
  float* myrow = A + (size_t)(k0 + tid) * NN + k0;
  float lgsum = 0.f;
  float rr[64];

  // ---- phase 1: panel factorization ----
  if (own) {
#pragma unroll
    for (int c4 = 0; c4 < 16; ++c4) {
      float4 v = *(const float4*)(myrow + c4 * 4);
      rr[c4 * 4 + 0] = v.x; rr[c4 * 4 + 1] = v.y;
      rr[c4 * 4 + 2] = v.z; rr[c4 * 4 + 3] = v.w;
    }
  } else {
#pragma unroll
    for (int c = 0; c < 64; ++c) rr[c] = 0.f;
  }
  if (tid == 0) {
    lgsum += logf(rr[0]);
#pragma unroll
    for (int c4 = 0; c4 < 16; ++c4) {
      float4 v = {rr[c4 * 4 + 0], rr[c4 * 4 + 1], rr[c4 * 4 + 2], rr[c4 * 4 + 3]};
      *(float4*)&Prow[0][c4 * 4] = v;
    }
  }
  __syncthreads();
  PStepF<0>::run(rr, Prow, own, tid, lgsum);
  // bulk rows: write back L21 multipliers (k_gemm stages them from global).
  // Pivot rows (tid<64) are dead data downstream (L11 goes via LDS): skip.
  if (own && tid >= 64) {
#pragma unroll
    for (int c4 = 0; c4 < 16; ++c4) {
      float4 v = {rr[c4 * 4 + 0], rr[c4 * 4 + 1], rr[c4 * 4 + 2], rr[c4 * 4 + 3]};
      *(float4*)(myrow + c4 * 4) = v;
    }
  }
  if (tid < 64) {  // publish full L11 rows (multipliers + U) for U12 solve
#pragma unroll
    for (int c4 = 0; c4 < 16; ++c4) {
      float4 v = {rr[c4 * 4 + 0], rr[c4 * 4 + 1], rr[c4 * 4 + 2], rr[c4 * 4 + 3]};
      *(float4*)&L11[tid * 68 + c4 * 4] = v;
    }
  }
  __syncthreads();

  // ---- phase 2: U12 = L11^{-1} A12; inactive waves skip (w % 64 == 0) ----
  if (w > 0 && tid < w) {
    int col = k0 + NB + tid;
#pragma unroll
    for (int t = 0; t < 64; ++t) rr[t] = A[(size_t)(k0 + t) * NN + col];
    UStep<0>::run(rr, L11);
#pragma unroll
    for (int t = 0; t < 64; ++t) A[(size_t)(k0 + t) * NN + col] = rr[t];
  }

  // ---- logdet partial ----
  float s = block_reduce_sum_512(lgsum, red);
  if (tid == 0) {
    int gi = m0 + slot;
    if (p == 0) ld[gi] = s;
    else        ld[gi] += s;
  }
}

// ---------------- trailing update A22 -= L21 * U12 ----------------
// grid (nt, nt, count), 256 threads, 128x128 tile, k = 64.
// At transposed [kk][r] stride 136; B-operand pipelined DEPTH 3 (named f4s).
__global__ __launch_bounds__(256)
void k_gemm(float* __restrict__ mats, int p) {
  __shared__ __align__(16) float At[64 * 136];  // 34.8 KB
  int k0 = p * NB;
  int w = NN - k0 - NB;
  float* A = mats + (size_t)blockIdx.z * NN2;
  int rb = blockIdx.x * 128, cb = blockIdx.y * 128;
  int tid = threadIdx.x;
#pragma unroll
  for (int it = 0; it < 32; ++it) {
    int idx = tid + it * 256;
    int r = idx >> 6, kk = idx & 63;
    int gr = rb + r;
    float v = 0.f;
    if (gr < w) v = A[(size_t)(k0 + NB + gr) * NN + k0 + kk];
    At[kk * 136 + r] = v;
  }
  __syncthreads();
  int ty = tid >> 4, tx = tid & 15;
  int r0 = ty * 8, c0 = tx * 8;
  int gc0 = k0 + NB + cb + c0;
  bool cok = (cb + c0) < w;
  float acc[8][8];
#pragma unroll
  for (int q = 0; q < 8; ++q)
#pragma unroll
    for (int u = 0; u < 8; ++u) acc[q][u] = 0.f;
  float4 bc0 = {0.f, 0.f, 0.f, 0.f}, bc1 = {0.f, 0.f, 0.f, 0.f};
  float4 bn0 = {0.f, 0.f, 0.f, 0.f}, bn1 = {0.f, 0.f, 0.f, 0.f};
  float4 bf0 = {0.f, 0.f, 0.f, 0.f}, bf1 = {0.f, 0.f, 0.f, 0.f};
  if (cok) {
    const float* Br0 = &A[(size_t)k0 * NN + gc0];
    bc0 = *(const float4*)Br0;
    bc1 = *(const float4*)(Br0 + 4);
    const float* Br1 = &A[(size_t)(k0 + 1) * NN + gc0];
    bn0 = *(const float4*)Br1;
    bn1 = *(const float4*)(Br1 + 4);
    const float* Br2 = &A[(size_t)(k0 + 2) * NN + gc0];
    bf0 = *(const float4*)Br2;
    bf1 = *(const float4*)(Br2 + 4);
  }
#pragma unroll 2
  for (int kk = 0; kk < 64; ++kk) {
    float4 bx0 = {0.f, 0.f, 0.f, 0.f}, bx1 = {0.f, 0.f, 0.f, 0.f};
    if (cok && kk < 61) {
      const float* Br = &A[(size_t)(k0 + kk + 3) * NN + gc0];
      bx0 = *(const float4*)Br;
      bx1 = *(const float4*)(Br + 4);
    }
    float4 a0 = *(const float4*)&At[kk * 136 + r0];
    float4 a1 = *(const float4*)&At[kk * 136 + r0 + 4];
    float la[8] = {a0.x, a0.y, a0.z, a0.w, a1.x, a1.y, a1.z, a1.w};
    float lb[8] = {bc0.x, bc0.y, bc0.z, bc0.w, bc1.x, bc1.y, bc1.z, bc1.w};
#pragma unroll
    for (int q = 0; q < 8; ++q)
#pragma unroll
      for (int u = 0; u < 8; ++u) acc[q][u] = fmaf(la[q], lb[u], acc[q][u]);
    bc0 = bn0; bc1 = bn1;
    bn0 = bf0; bn1 = bf1;
    bf0 = bx0; bf1 = bx1;
  }
  if (!cok) return;
#pragma unroll
  for (int q = 0; q < 8; ++q) {
    int gr = rb + r0 + q;
    if (gr < w) {
      float* dst = &A[(size_t)(k0 + NB + gr) * NN + gc0];
      float4 v0 = *(const float4*)dst;
      float4 v1 = *(const float4*)(dst + 4);
      v0.x -= acc[q][0]; v0.y -= acc[q][1]; v0.z -= acc[q][2]; v0.w -= acc[q][3];
      v1.x -= acc[q][4]; v1.y -= acc[q][5]; v1.z -= acc[q][6]; v1.w -= acc[q][7];
      *(float4*)dst = v0;
      *(float4*)(dst + 4) = v1;
    }
  }
}

// ---------------- final combine ----------------
__global__ void k_y(const float* __restrict__ logPr, const float* __restrict__ ld,
                    float* __restrict__ y) {
  int b = threadIdx.x;
  if (b < BATCH) y[b] = logPr[b] + ld[b] - ld[BATCH];
}

extern "C" void kernel_launch(void* const* d_in, const int* in_sizes, int n_in,
                              void* d_out, int out_size, void* d_ws, size_t ws_size,
                              hipStream_t stream) {
  const int* x = (const int*)d_in[0];
  const float* W = (const float*)d_in[1];
  const float* Vc = (const float*)d_in[2];
  const float* Ec = (const float*)d_in[3];
  float* out = (float*)d_out;

  char* ws = (char*)d_ws;
  size_t off = 0;
  auto alloc = [&](size_t bytes) -> void* {
    void* pp = ws + off;
    off = (off + bytes + 255) & ~(size_t)255;
    return pp;
  };
  float* V     = (float*)alloc((size_t)NN * 4 * 4);
  float* Wsbuf = (float*)alloc(NN2 * 4);
  float* rPr   = (float*)alloc((size_t)BATCH * NN * 4);
  float* logPr = (float*)alloc((size_t)BATCH * 4);
  float* ld    = (float*)alloc((size_t)NMAT * 4);
  float* E     = (float*)alloc(NN2 * 16 * 4);
  size_t per_mat = NN2 * 4;
  size_t remain = ws_size > off ? ws_size - off : 0;
  int cap = (int)(remain / per_mat);
  if (cap > NMAT) cap = NMAT;
  if (cap < 1) cap = 1;
  float* mats = (float*)(ws + off);

  k_softmaxV<<<1, 512, 0, stream>>>(Vc, V);
  k_Ws<<<NN, NN, 0, stream>>>(W, Wsbuf);
  k_E<<<(NN * NN) / 256, 256, 0, stream>>>(Ec, V, E);
  k_Pr<<<BATCH, NN, 0, stream>>>(x, V, rPr, logPr);

  for (int m0 = 0; m0 < NMAT; m0 += cap) {
    int cnt = NMAT - m0 < cap ? NMAT - m0 : cap;
    dim3 gb(64, cnt);
    k_build<<<gb, 512, 0, stream>>>(x, Wsbuf, E, rPr, mats, m0);
    for (int p = 0; p < 8; ++p) {
      k_pu<<<cnt, 512, 0, stream>>>(mats, ld, m0, p);
      int w = NN - p * NB - NB;
      if (w > 0) {
        int nt = (w + 127) / 128;
        dim3 gg(nt, nt, cnt);
        k_gemm<<<gg, 256, 0, stream>>>(mats, p);
      }
    }
  }
  k_y<<<1, 256, 0, stream>>>(logPr, ld, out);
}